// Round 5
// baseline (130.435 us; speedup 1.0000x reference)
//
#include <hip/hip_runtime.h>
#include <math.h>

// Problem constants
#define NB   4
#define CH   256
#define HW   4096          // 64*64
#define NCOL 216           // 144 offset + 72 mask
#define MTOT 16384         // NB*HW
#define CHW  1048576       // CH*HW
#define EPSV 1e-5f

// ws layout in floats (identical footprint to the 146us session)
#define OFF_NHWC 0
#define NHWCSZ   (NB*HW*CH/2)          // bf16 NHWC raw input
#define OFF_OM   (OFF_NHWC + NHWCSZ)   // (unused)
#define OMSZ     (MTOT*NCOL/2)
#define OFF_AB   (OFF_OM + OMSZ)       // A bf16 [M][256]
#define ABSZ     (MTOT*CH/2)
#define OFF_WB   (OFF_AB + ABSZ)       // Wc_bt bf16 [256][256]
#define WBSZ     (CH*CH/2)
#define OFF_BI   (OFF_WB + WBSZ)       // bias 256 (216 used)
#define OFF_PT   (OFF_BI + 256)        // partials 4096*2

typedef short bf16x8 __attribute__((ext_vector_type(8)));
typedef float f32x4  __attribute__((ext_vector_type(4)));

__device__ __forceinline__ unsigned short f2bf(float f) {
    unsigned int u = __builtin_bit_cast(unsigned int, f);
    u += 0x7fffu + ((u >> 16) & 1u);           // round-to-nearest-even
    return (unsigned short)(u >> 16);
}

__device__ __forceinline__ float bf2f(unsigned short s) {
    return __builtin_bit_cast(float, (unsigned int)s << 16);
}

// ---- fused: depthwise conv -> bf16 A [m][k] + partials + bf16 NHWC raw x
//      + weight prep (blocks 0..255) + bias (block 0) ----
// grid: 4 n * 8 ctile * 128 hwtile = 4096 blocks; block 256.  (unchanged)
__global__ __launch_bounds__(256) void conv_prep_kernel(
    const float* __restrict__ x, const float* __restrict__ dw_w,
    const float* __restrict__ dw_b,
    const float* __restrict__ off_w, const float* __restrict__ off_b,
    const float* __restrict__ mask_w, const float* __restrict__ mask_b,
    unsigned short* __restrict__ A, unsigned short* __restrict__ inp_nhwc,
    unsigned short* __restrict__ Wc_bt, float* __restrict__ bias,
    float* __restrict__ partials) {
    __shared__ float xs[32 * 120];         // [32ch][3row][40col]
    __shared__ unsigned short tb[32 * 36]; // [32pix][36], 32 ch used
    __shared__ float rs1[4], rs2[4];
    int b = blockIdx.x;
    int tid = threadIdx.x;
    // weight prep: block b < 256 handles k=b, all n
    if (b < 256) {
        int k = b, n = tid;
        float v = 0.f;
        if (n < 144)      v = off_w[k * 144 + n];
        else if (n < 216) v = mask_w[k * 72 + (n - 144)];
        Wc_bt[(size_t)n * 256 + k] = f2bf(v);
        if (b == 0) {
            float bb = 0.f;
            if (n < 144)      bb = off_b[n];
            else if (n < 216) bb = mask_b[n - 144];
            bias[n] = bb;
        }
    }
    int ct  = b & 7;
    int hwt = (b >> 3) & 127;
    int n   = b >> 10;
    int c0 = ct * 32;
    int hw0 = hwt * 32;
    int h  = hw0 >> 6;
    int w0 = hw0 & 63;
    const float* xb = x + ((size_t)n * CH + c0) * HW;
    // interior halo: float4 columns gw in [w0, w0+31] (w0 % 32 == 0 -> aligned)
#pragma unroll
    for (int it = 0; it < 3; ++it) {
        int idx = it * 256 + tid;          // < 768 = 32ch * 3r * 8 f4
        int cl  = idx / 24;
        int rem = idx - cl * 24;
        int r   = rem >> 3;
        int f4  = rem & 7;
        int gh  = h - 1 + r;
        float4 v = make_float4(0.f, 0.f, 0.f, 0.f);
        if (gh >= 0 && gh < 64)
            v = *(const float4*)&xb[(size_t)cl * HW + gh * 64 + w0 + f4 * 4];
        *(float4*)&xs[cl * 120 + r * 40 + 4 + f4 * 4] = v;
    }
    // edge halo: gw = w0-1 (pos 3) and gw = w0+32 (pos 36)
    if (tid < 192) {
        int cl   = tid / 6;
        int rem  = tid - cl * 6;
        int r    = rem >> 1;
        int side = rem & 1;
        int gh   = h - 1 + r;
        int gw   = side ? (w0 + 32) : (w0 - 1);
        float v = 0.f;
        if (gh >= 0 && gh < 64 && gw >= 0 && gw < 64)
            v = xb[(size_t)cl * HW + gh * 64 + gw];
        xs[cl * 120 + r * 40 + (side ? 36 : 3)] = v;
    }
    __syncthreads();
    int wl = tid & 31;            // local pixel
    int cbase = (tid >> 5) * 4;   // 4 channels per thread
    float s1 = 0.f, s2 = 0.f;
    ushort4 o;
    unsigned short ov[4];
#pragma unroll
    for (int j = 0; j < 4; ++j) {
        int c = c0 + cbase + j;
        float acc = dw_b[c];
        const float* wk = dw_w + c * 9;
#pragma unroll
        for (int r = 0; r < 3; ++r)
#pragma unroll
            for (int kx = 0; kx < 3; ++kx)
                acc = fmaf(xs[(cbase + j) * 120 + r * 40 + wl + kx + 3], wk[r * 3 + kx], acc);
        s1 += acc; s2 += acc * acc;
        ov[j] = f2bf(acc);
    }
    o.x = ov[0]; o.y = ov[1]; o.z = ov[2]; o.w = ov[3];
    *(ushort4*)&tb[wl * 36 + cbase] = o;
    // wave-level stats reduce: 6 shuffles, then 4 LDS slots
#pragma unroll
    for (int off = 32; off >= 1; off >>= 1) {
        s1 += __shfl_xor(s1, off, 64);
        s2 += __shfl_xor(s2, off, 64);
    }
    if ((tid & 63) == 0) { rs1[tid >> 6] = s1; rs2[tid >> 6] = s2; }
    // write raw x (center row) as bf16 NHWC, straight from xs
    {
        int r2 = tid >> 3, cg = tid & 7;      // pixel, 4-ch group
        ushort4 rv;
        rv.x = f2bf(xs[(cg * 4 + 0) * 120 + 40 + r2 + 4]);
        rv.y = f2bf(xs[(cg * 4 + 1) * 120 + 40 + r2 + 4]);
        rv.z = f2bf(xs[(cg * 4 + 2) * 120 + 40 + r2 + 4]);
        rv.w = f2bf(xs[(cg * 4 + 3) * 120 + 40 + r2 + 4]);
        *(ushort4*)&inp_nhwc[((size_t)(n * HW + hw0 + r2)) * 256 + c0 + cg * 4] = rv;
    }
    __syncthreads();   // protects tb (A-write) and rs (partials)
    if (tid == 0) {
        partials[2 * b]     = rs1[0] + rs1[1] + rs1[2] + rs1[3];
        partials[2 * b + 1] = rs2[0] + rs2[1] + rs2[2] + rs2[3];
    }
    // write A bf16 [m][k], 8B per lane, 8 lanes per m-row
    int r2 = tid >> 3, cg = tid & 7;
    ushort4 w4 = *(const ushort4*)&tb[r2 * 36 + cg * 4];
    *(ushort4*)&A[((size_t)(n * HW + hw0 + r2)) * 256 + c0 + cg * 4] = w4;
}

// ============ fused: stats + norm/gelu GEMM + DCNv3 + NCHW output ============
// R5: latency fix. 512 blocks x 512 thr; block = HALF an image row (32 px).
// LDS regions aliased (ot reuses As/Bs after the GEMM): 67.6 KB/block ->
// 2 blocks/CU = 16 waves/CU (was 1 block, 8 waves). __launch_bounds__(512,4)
// caps VGPR at 128 so occupancy is LDS-limited, not VGPR-limited.
#define LDK 72
#define SM_LOM   0                      // float[32*216]          27648 B
#define SM_AS    27648                  // ushort[32*72]           4608 B
#define SM_BS    (27648 + 4608)         // ushort[256*72]         36864 B
#define SM_OT    27648                  // float[16*260] (aliases As/Bs)
#define SM_RED   69120                  // float[8] + float[8]       64 B
#define SM_SZ    69184
__global__ __launch_bounds__(512, 4) void fused_gemm_dcn_kernel(
    const unsigned short* __restrict__ A, const unsigned short* __restrict__ Bt,
    const float* __restrict__ bias, const float* __restrict__ partials,
    const float* __restrict__ gn_g, const float* __restrict__ gn_b,
    const unsigned short* __restrict__ inp_nhwc, float* __restrict__ out) {
    __shared__ __align__(16) char smem[SM_SZ];
    float* lom          = (float*)(smem + SM_LOM);
    unsigned short* As  = (unsigned short*)(smem + SM_AS);
    unsigned short* Bs  = (unsigned short*)(smem + SM_BS);
    float* ot           = (float*)(smem + SM_OT);
    float* red1         = (float*)(smem + SM_RED);
    float* red2         = red1 + 8;

    int bid = blockIdx.x;
    int tile = (bid & 7) * 64 + (bid >> 3);   // 512 % 8 == 0 -> bijective
    int m0 = tile * 32;                       // half an image row
    int n = m0 >> 12;
    int hwb = m0 & 4095;                      // hwb % 32 == 0
    int tid = threadIdx.x, lane = tid & 63, wid = tid >> 6;

    // ---- phase 0: pre-stage B for k0=0 (independent of stats) ----
#pragma unroll
    for (int i = 0; i < 4; ++i) {
        int q = i * 512 + tid;
        int mm = q >> 3, kk = (q & 7) * 8;
        *(uint4*)&Bs[mm * LDK + kk] = *(const uint4*)&Bt[(size_t)mm * 256 + kk];
    }

    // ---- phase 1: per-sample GroupNorm stats (shuffle reduce, 1 barrier) ----
    {
        const float2* p2 = (const float2*)partials;
        float2 a = p2[n * 1024 + tid];
        float2 c = p2[n * 1024 + tid + 512];
        float s1 = a.x + c.x, s2 = a.y + c.y;
#pragma unroll
        for (int off = 32; off >= 1; off >>= 1) {
            s1 += __shfl_xor(s1, off, 64);
            s2 += __shfl_xor(s2, off, 64);
        }
        if (lane == 0) { red1[wid] = s1; red2[wid] = s2; }
    }
    __syncthreads();    // protects red AND the k0=0 Bs staging
    float t1 = 0.f, t2 = 0.f;
#pragma unroll
    for (int i = 0; i < 8; ++i) { t1 += red1[i]; t2 += red2[i]; }
    float mean = t1 * (1.f / (float)CHW);
    float var  = t2 * (1.f / (float)CHW) - mean * mean;
    float rsig = rsqrtf(var + EPSV);

    // ---- phase 2: GEMM (32m x 256n, K=256) -> lom (fp32) ----
    f32x4 acc[2][2] = {};
    for (int k0 = 0; k0 < 256; k0 += 64) {
        // stage A (32x64) with norm+gelu: one uint2 (4 elems) per thread
        {
            int row = tid >> 4, kk0 = (tid & 15) * 4;
            union { uint2 u; unsigned short s[4]; } in, ou;
            in.u = *(const uint2*)&A[((size_t)(m0 + row)) * 256 + k0 + kk0];
#pragma unroll
            for (int j = 0; j < 4; ++j) {
                int ch = k0 + kk0 + j;
                float v = bf2f(in.s[j]);
                v = (v - mean) * rsig * gn_g[ch] + gn_b[ch];
                v = 0.5f * v * (1.0f + erff(v * 0.70710678118654752f));
                ou.s[j] = f2bf(v);
            }
            *(uint2*)&As[row * LDK + kk0] = ou.u;
        }
        // stage B (256x64) — k0=0 already staged in phase 0
        if (k0) {
#pragma unroll
            for (int i = 0; i < 4; ++i) {
                int q = i * 512 + tid;
                int mm = q >> 3, kk = (q & 7) * 8;
                *(uint4*)&Bs[mm * LDK + kk] = *(const uint4*)&Bt[(size_t)mm * 256 + k0 + kk];
            }
        }
        __syncthreads();
#pragma unroll
        for (int kh = 0; kh < 2; ++kh) {
            bf16x8 af[2], bfr[2];
#pragma unroll
            for (int mi = 0; mi < 2; ++mi)
                af[mi] = *(const bf16x8*)&As[(mi * 16 + (lane & 15)) * LDK + kh * 32 + (lane >> 4) * 8];
#pragma unroll
            for (int nj = 0; nj < 2; ++nj)
                bfr[nj] = *(const bf16x8*)&Bs[(wid * 32 + nj * 16 + (lane & 15)) * LDK + kh * 32 + (lane >> 4) * 8];
#pragma unroll
            for (int mi = 0; mi < 2; ++mi)
#pragma unroll
                for (int nj = 0; nj < 2; ++nj)
                    acc[mi][nj] = __builtin_amdgcn_mfma_f32_16x16x32_bf16(
                        af[mi], bfr[nj], acc[mi][nj], 0, 0, 0);
        }
        __syncthreads();
    }
    // epilogue: acc + bias -> lom[32][216] fp32
#pragma unroll
    for (int nj = 0; nj < 2; ++nj) {
        int col = wid * 32 + nj * 16 + (lane & 15);
        if (col < NCOL) {
            float bcol = bias[col];
#pragma unroll
            for (int mi = 0; mi < 2; ++mi)
#pragma unroll
                for (int r = 0; r < 4; ++r) {
                    int row = mi * 16 + (lane >> 4) * 4 + r;
                    lom[row * NCOL + col] = acc[mi][nj][r] + bcol;
                }
        }
    }
    __syncthreads();   // lom ready; also last use of As/Bs is done -> ot may alias

    // ---- phase 3: DCNv3 gather, 2 rounds x 16 pixels ----
    const unsigned short* base = inp_nhwc + (size_t)n * HW * 256;
    int half = tid >> 5;              // 0..15: pixel slot within round
    int l  = tid & 31;                // lane-in-half-wave
    int g  = l >> 2;                  // group (4 lanes/group)
    int ch0 = l * 8;                  // 8 channels per lane
#pragma unroll
    for (int round = 0; round < 2; ++round) {
        int pixloc = round * 16 + half;
        int hw = hwb + pixloc;
        int h = hw >> 6, w = hw & 63;
        const float* lm = &lom[pixloc * NCOL];
        // softmax over P for this group
        float lg[9];
        float mx = -1e30f;
#pragma unroll
        for (int p = 0; p < 9; ++p) { lg[p] = lm[144 + g * 9 + p]; mx = fmaxf(mx, lg[p]); }
        float sum = 0.f;
#pragma unroll
        for (int p = 0; p < 9; ++p) { lg[p] = __expf(lg[p] - mx); sum += lg[p]; }
        float rs = 1.0f / sum;
        float acc2[8] = {};
#pragma unroll
        for (int p = 0; p < 9; ++p) {
            float ox = lm[g * 18 + p * 2];
            float oy = lm[g * 18 + p * 2 + 1];
            // padded coords; pad ring is zeros -> valid iff 1<=idx<=64
            float px = (float)(w + (p / 3)) + ox;
            float py = (float)(h + (p % 3)) + oy;
            float xf = floorf(px), yf = floorf(py);
            float wx = px - xf, wy = py - yf;
            int x0 = (int)xf, y0 = (int)yf;
            float m = lg[p] * rs;
            float w00 = m * (1.f - wy) * (1.f - wx);
            float w01 = m * (1.f - wy) * wx;
            float w10 = m * wy * (1.f - wx);
            float w11 = m * wy * wx;
#pragma unroll
            for (int corner = 0; corner < 4; ++corner) {
                int yi = y0 + (corner >> 1);
                int xi = x0 + (corner & 1);
                float cw = (corner == 0) ? w00 : (corner == 1) ? w01 : (corner == 2) ? w10 : w11;
                bool valid = (yi >= 1) & (yi <= 64) & (xi >= 1) & (xi <= 64);
                int yc = min(max(yi, 1), 64) - 1;
                int xc = min(max(xi, 1), 64) - 1;
                bf16x8 v = *(const bf16x8*)&base[((size_t)yc * 64 + xc) * 256 + ch0];
                float f = valid ? cw : 0.f;
#pragma unroll
                for (int j = 0; j < 8; ++j)
                    acc2[j] = fmaf(f, bf2f((unsigned short)v[j]), acc2[j]);
            }
        }
        *(float4*)&ot[half * 260 + ch0]     = make_float4(acc2[0], acc2[1], acc2[2], acc2[3]);
        *(float4*)&ot[half * 260 + ch0 + 4] = make_float4(acc2[4], acc2[5], acc2[6], acc2[7]);
        __syncthreads();
        // write NCHW: 16 consecutive pixels per channel (64B segments)
        int px = tid & 15, crow = tid >> 4;   // crow 0..31
#pragma unroll
        for (int cc = 0; cc < 8; ++cc) {
            int c = cc * 32 + crow;
            out[((size_t)(n * CH + c)) * HW + hwb + round * 16 + px] = ot[px * 260 + c];
        }
        if (round == 0) __syncthreads();   // protect ot before next round's writes
    }
}

extern "C" void kernel_launch(void* const* d_in, const int* in_sizes, int n_in,
                              void* d_out, int out_size, void* d_ws, size_t ws_size,
                              hipStream_t stream) {
    const float* x      = (const float*)d_in[0];
    const float* dw_w   = (const float*)d_in[1];
    const float* dw_b   = (const float*)d_in[2];
    const float* gn_g   = (const float*)d_in[3];
    const float* gn_b   = (const float*)d_in[4];
    const float* off_w  = (const float*)d_in[5];
    const float* off_b  = (const float*)d_in[6];
    const float* mask_w = (const float*)d_in[7];
    const float* mask_b = (const float*)d_in[8];
    float* out = (float*)d_out;

    float* ws = (float*)d_ws;
    unsigned short* inp_nhwc = (unsigned short*)(ws + OFF_NHWC);
    unsigned short* Abf   = (unsigned short*)(ws + OFF_AB);
    unsigned short* Wc_bt = (unsigned short*)(ws + OFF_WB);
    float* bias     = ws + OFF_BI;
    float* partials = ws + OFF_PT;

    conv_prep_kernel<<<4096, 256, 0, stream>>>(x, dw_w, dw_b, off_w, off_b,
                                               mask_w, mask_b, Abf, inp_nhwc,
                                               Wc_bt, bias, partials);
    fused_gemm_dcn_kernel<<<512, 512, 0, stream>>>(Abf, Wc_bt, bias, partials,
                                                   gn_g, gn_b, inp_nhwc, out);
}

// Round 6
// 118.821 us; speedup vs baseline: 1.0977x; 1.0977x over previous
//
#include <hip/hip_runtime.h>
#include <math.h>

// Problem constants
#define NB   4
#define CH   256
#define HW   4096          // 64*64
#define PW   66            // padded width/height
#define PHW  4356          // 66*66
#define NCOL 216           // 144 offset + 72 mask
#define MTOT 16384         // NB*HW
#define CHW  1048576       // CH*HW
#define EPSV 1e-5f

// ws layout in floats (same total footprint as the 146us session; padded
// NHWC (2.23M floats) spans its old slot + the now-unused offmask slot)
#define OFF_NHWC 0
#define NHWCSZ   (NB*HW*CH/2)          // (old size; padded buf extends into OM)
#define OFF_OM   (OFF_NHWC + NHWCSZ)
#define OMSZ     (MTOT*NCOL/2)
#define OFF_AB   (OFF_OM + OMSZ)       // A bf16 [M][256]
#define ABSZ     (MTOT*CH/2)
#define OFF_WB   (OFF_AB + ABSZ)       // Wc_bt bf16 [256][256]
#define WBSZ     (CH*CH/2)
#define OFF_BI   (OFF_WB + WBSZ)       // bias 256 (216 used)
#define OFF_PT   (OFF_BI + 256)        // partials 4096*2

typedef short bf16x8 __attribute__((ext_vector_type(8)));
typedef float f32x4  __attribute__((ext_vector_type(4)));

__device__ __forceinline__ unsigned short f2bf(float f) {
    unsigned int u = __builtin_bit_cast(unsigned int, f);
    u += 0x7fffu + ((u >> 16) & 1u);           // round-to-nearest-even
    return (unsigned short)(u >> 16);
}

__device__ __forceinline__ float bf2f(unsigned short s) {
    return __builtin_bit_cast(float, (unsigned int)s << 16);
}

// gelu with A&S 7.1.26 erf (|err| <= 1.5e-7 abs, branch-free, ~13 VALU ops
// vs ~35 for OCML erff). Error is 4 orders below the bf16 round applied next.
__device__ __forceinline__ float gelu_fast(float v) {
    float x  = v * 0.70710678118654752f;
    float ax = fabsf(x);
    float t  = __builtin_amdgcn_rcpf(fmaf(0.3275911f, ax, 1.0f));
    float p  = fmaf(fmaf(fmaf(fmaf(1.061405429f, t, -1.453152027f), t,
                              1.421413741f), t, -0.284496736f), t, 0.254829592f);
    float e  = __expf(-x * x);
    float er = fmaf(-p * t, e, 1.0f);          // erf(|x|)
    er = copysignf(er, x);
    return 0.5f * v * (1.0f + er);
}

// ---- fused: depthwise conv -> bf16 A [m][k] + partials + bf16 PADDED NHWC x
//      + weight prep (blocks 0..255) + zero-ring (blocks 0..259) ----
// grid: 4 n * 8 ctile * 128 hwtile = 4096 blocks; block 256.
__global__ __launch_bounds__(256) void conv_prep_kernel(
    const float* __restrict__ x, const float* __restrict__ dw_w,
    const float* __restrict__ dw_b,
    const float* __restrict__ off_w, const float* __restrict__ off_b,
    const float* __restrict__ mask_w, const float* __restrict__ mask_b,
    unsigned short* __restrict__ A, unsigned short* __restrict__ inp_nhwc,
    unsigned short* __restrict__ Wc_bt, float* __restrict__ bias,
    float* __restrict__ partials) {
    __shared__ float xs[32 * 120];         // [32ch][3row][40col]
    __shared__ unsigned short tb[32 * 36]; // [32pix][36], 32 ch used
    __shared__ float rs1[4], rs2[4];
    int b = blockIdx.x;
    int tid = threadIdx.x;
    // weight prep: block b < 256 handles k=b, all n
    if (b < 256) {
        int k = b, n = tid;
        float v = 0.f;
        if (n < 144)      v = off_w[k * 144 + n];
        else if (n < 216) v = mask_w[k * 72 + (n - 144)];
        Wc_bt[(size_t)n * 256 + k] = f2bf(v);
        if (b == 0) {
            float bb = 0.f;
            if (n < 144)      bb = off_b[n];
            else if (n < 216) bb = mask_b[n - 144];
            bias[n] = bb;
        }
    }
    // zero ring of the padded NHWC image: 260 ring pixels per sample
    if (b < 260) {
        int rp = b, y, xq;
        if      (rp < 66)  { y = 0;        xq = rp; }
        else if (rp < 132) { y = 65;       xq = rp - 66; }
        else if (rp < 196) { y = rp - 131; xq = 0; }
        else               { y = rp - 195; xq = 65; }
#pragma unroll
        for (int n = 0; n < NB; ++n)
            inp_nhwc[((size_t)n * PHW + y * PW + xq) * 256 + tid] = 0;
    }
    int ct  = b & 7;
    int hwt = (b >> 3) & 127;
    int n   = b >> 10;
    int c0 = ct * 32;
    int hw0 = hwt * 32;
    int h  = hw0 >> 6;
    int w0 = hw0 & 63;
    const float* xb = x + ((size_t)n * CH + c0) * HW;
    // interior halo: float4 columns gw in [w0, w0+31] (w0 % 32 == 0 -> aligned)
#pragma unroll
    for (int it = 0; it < 3; ++it) {
        int idx = it * 256 + tid;          // < 768 = 32ch * 3r * 8 f4
        int cl  = idx / 24;
        int rem = idx - cl * 24;
        int r   = rem >> 3;
        int f4  = rem & 7;
        int gh  = h - 1 + r;
        float4 v = make_float4(0.f, 0.f, 0.f, 0.f);
        if (gh >= 0 && gh < 64)
            v = *(const float4*)&xb[(size_t)cl * HW + gh * 64 + w0 + f4 * 4];
        *(float4*)&xs[cl * 120 + r * 40 + 4 + f4 * 4] = v;
    }
    // edge halo: gw = w0-1 (pos 3) and gw = w0+32 (pos 36)
    if (tid < 192) {
        int cl   = tid / 6;
        int rem  = tid - cl * 6;
        int r    = rem >> 1;
        int side = rem & 1;
        int gh   = h - 1 + r;
        int gw   = side ? (w0 + 32) : (w0 - 1);
        float v = 0.f;
        if (gh >= 0 && gh < 64 && gw >= 0 && gw < 64)
            v = xb[(size_t)cl * HW + gh * 64 + gw];
        xs[cl * 120 + r * 40 + (side ? 36 : 3)] = v;
    }
    __syncthreads();
    int wl = tid & 31;            // local pixel
    int cbase = (tid >> 5) * 4;   // 4 channels per thread
    float s1 = 0.f, s2 = 0.f;
    ushort4 o;
    unsigned short ov[4];
#pragma unroll
    for (int j = 0; j < 4; ++j) {
        int c = c0 + cbase + j;
        float acc = dw_b[c];
        const float* wk = dw_w + c * 9;
#pragma unroll
        for (int r = 0; r < 3; ++r)
#pragma unroll
            for (int kx = 0; kx < 3; ++kx)
                acc = fmaf(xs[(cbase + j) * 120 + r * 40 + wl + kx + 3], wk[r * 3 + kx], acc);
        s1 += acc; s2 += acc * acc;
        ov[j] = f2bf(acc);
    }
    o.x = ov[0]; o.y = ov[1]; o.z = ov[2]; o.w = ov[3];
    *(ushort4*)&tb[wl * 36 + cbase] = o;
    // wave-level stats reduce: 6 shuffles, then 4 LDS slots
#pragma unroll
    for (int off = 32; off >= 1; off >>= 1) {
        s1 += __shfl_xor(s1, off, 64);
        s2 += __shfl_xor(s2, off, 64);
    }
    if ((tid & 63) == 0) { rs1[tid >> 6] = s1; rs2[tid >> 6] = s2; }
    // write raw x (center row) as bf16 into PADDED NHWC at (h+1, w+1)
    {
        int r2 = tid >> 3, cg = tid & 7;      // pixel, 4-ch group
        ushort4 rv;
        rv.x = f2bf(xs[(cg * 4 + 0) * 120 + 40 + r2 + 4]);
        rv.y = f2bf(xs[(cg * 4 + 1) * 120 + 40 + r2 + 4]);
        rv.z = f2bf(xs[(cg * 4 + 2) * 120 + 40 + r2 + 4]);
        rv.w = f2bf(xs[(cg * 4 + 3) * 120 + 40 + r2 + 4]);
        size_t pbase = ((size_t)n * PHW + (h + 1) * PW + w0 + r2 + 1) * 256;
        *(ushort4*)&inp_nhwc[pbase + c0 + cg * 4] = rv;
    }
    __syncthreads();   // protects tb (A-write) and rs (partials)
    if (tid == 0) {
        partials[2 * b]     = rs1[0] + rs1[1] + rs1[2] + rs1[3];
        partials[2 * b + 1] = rs2[0] + rs2[1] + rs2[2] + rs2[3];
    }
    // write A bf16 [m][k], 8B per lane, 8 lanes per m-row
    int r2 = tid >> 3, cg = tid & 7;
    ushort4 w4 = *(const ushort4*)&tb[r2 * 36 + cg * 4];
    *(ushort4*)&A[((size_t)(n * HW + hw0 + r2)) * 256 + c0 + cg * 4] = w4;
}

// ============ fused: stats + norm/gelu GEMM + DCNv3 + NCHW output ============
// 512 blocks x 512 thr; block = half an image row (32 px); LDS aliased ->
// 67.6 KB, 2 blocks/CU, 16 waves/CU (VGPR-capped max). Padded-image gather:
// clamp into the zero ring replaces the valid-mask exactly (ring = 0).
#define LDK 72
#define SM_LOM   0                      // float[32*216]          27648 B
#define SM_AS    27648                  // ushort[32*72]           4608 B
#define SM_BS    (27648 + 4608)         // ushort[256*72]         36864 B
#define SM_OT    27648                  // float[16*260] (aliases As/Bs)
#define SM_RED   69120                  // float[8] + float[8]       64 B
#define SM_SZ    69184
__global__ __launch_bounds__(512, 4) void fused_gemm_dcn_kernel(
    const unsigned short* __restrict__ A, const unsigned short* __restrict__ Bt,
    const float* __restrict__ bias, const float* __restrict__ partials,
    const float* __restrict__ gn_g, const float* __restrict__ gn_b,
    const unsigned short* __restrict__ inp_nhwc, float* __restrict__ out) {
    __shared__ __align__(16) char smem[SM_SZ];
    float* lom          = (float*)(smem + SM_LOM);
    unsigned short* As  = (unsigned short*)(smem + SM_AS);
    unsigned short* Bs  = (unsigned short*)(smem + SM_BS);
    float* ot           = (float*)(smem + SM_OT);
    float* red1         = (float*)(smem + SM_RED);
    float* red2         = red1 + 8;

    int bid = blockIdx.x;
    int tile = (bid & 7) * 64 + (bid >> 3);   // 512 % 8 == 0 -> bijective
    int m0 = tile * 32;                       // half an image row
    int n = m0 >> 12;
    int hwb = m0 & 4095;                      // hwb % 32 == 0
    int tid = threadIdx.x, lane = tid & 63, wid = tid >> 6;

    // ---- phase 0: pre-stage B for k0=0 (independent of stats) ----
#pragma unroll
    for (int i = 0; i < 4; ++i) {
        int q = i * 512 + tid;
        int mm = q >> 3, kk = (q & 7) * 8;
        *(uint4*)&Bs[mm * LDK + kk] = *(const uint4*)&Bt[(size_t)mm * 256 + kk];
    }

    // ---- phase 1: per-sample GroupNorm stats (shuffle reduce, 1 barrier) ----
    {
        const float2* p2 = (const float2*)partials;
        float2 a = p2[n * 1024 + tid];
        float2 c = p2[n * 1024 + tid + 512];
        float s1 = a.x + c.x, s2 = a.y + c.y;
#pragma unroll
        for (int off = 32; off >= 1; off >>= 1) {
            s1 += __shfl_xor(s1, off, 64);
            s2 += __shfl_xor(s2, off, 64);
        }
        if (lane == 0) { red1[wid] = s1; red2[wid] = s2; }
    }
    __syncthreads();    // protects red AND the k0=0 Bs staging
    float t1 = 0.f, t2 = 0.f;
#pragma unroll
    for (int i = 0; i < 8; ++i) { t1 += red1[i]; t2 += red2[i]; }
    float mean = t1 * (1.f / (float)CHW);
    float var  = t2 * (1.f / (float)CHW) - mean * mean;
    float rsig = rsqrtf(var + EPSV);

    // ---- phase 2: GEMM (32m x 256n, K=256) -> lom (fp32) ----
    f32x4 acc[2][2] = {};
    for (int k0 = 0; k0 < 256; k0 += 64) {
        // stage A (32x64) with norm+gelu: one uint2 (4 elems) per thread
        {
            int row = tid >> 4, kk0 = (tid & 15) * 4;
            union { uint2 u; unsigned short s[4]; } in, ou;
            in.u = *(const uint2*)&A[((size_t)(m0 + row)) * 256 + k0 + kk0];
#pragma unroll
            for (int j = 0; j < 4; ++j) {
                int ch = k0 + kk0 + j;
                float v = bf2f(in.s[j]);
                v = (v - mean) * rsig * gn_g[ch] + gn_b[ch];
                ou.s[j] = f2bf(gelu_fast(v));
            }
            *(uint2*)&As[row * LDK + kk0] = ou.u;
        }
        // stage B (256x64) — k0=0 already staged in phase 0
        if (k0) {
#pragma unroll
            for (int i = 0; i < 4; ++i) {
                int q = i * 512 + tid;
                int mm = q >> 3, kk = (q & 7) * 8;
                *(uint4*)&Bs[mm * LDK + kk] = *(const uint4*)&Bt[(size_t)mm * 256 + k0 + kk];
            }
        }
        __syncthreads();
#pragma unroll
        for (int kh = 0; kh < 2; ++kh) {
            bf16x8 af[2], bfr[2];
#pragma unroll
            for (int mi = 0; mi < 2; ++mi)
                af[mi] = *(const bf16x8*)&As[(mi * 16 + (lane & 15)) * LDK + kh * 32 + (lane >> 4) * 8];
#pragma unroll
            for (int nj = 0; nj < 2; ++nj)
                bfr[nj] = *(const bf16x8*)&Bs[(wid * 32 + nj * 16 + (lane & 15)) * LDK + kh * 32 + (lane >> 4) * 8];
#pragma unroll
            for (int mi = 0; mi < 2; ++mi)
#pragma unroll
                for (int nj = 0; nj < 2; ++nj)
                    acc[mi][nj] = __builtin_amdgcn_mfma_f32_16x16x32_bf16(
                        af[mi], bfr[nj], acc[mi][nj], 0, 0, 0);
        }
        __syncthreads();
    }
    // epilogue: acc + bias -> lom[32][216] fp32
#pragma unroll
    for (int nj = 0; nj < 2; ++nj) {
        int col = wid * 32 + nj * 16 + (lane & 15);
        if (col < NCOL) {
            float bcol = bias[col];
#pragma unroll
            for (int mi = 0; mi < 2; ++mi)
#pragma unroll
                for (int r = 0; r < 4; ++r) {
                    int row = mi * 16 + (lane >> 4) * 4 + r;
                    lom[row * NCOL + col] = acc[mi][nj][r] + bcol;
                }
        }
    }
    __syncthreads();   // lom ready; also last use of As/Bs is done -> ot may alias

    // ---- phase 3: DCNv3 gather, 2 rounds x 16 pixels (padded image) ----
    const unsigned short* base = inp_nhwc + (size_t)n * PHW * 256;
    int half = tid >> 5;              // 0..15: pixel slot within round
    int l  = tid & 31;                // lane-in-half-wave
    int g  = l >> 2;                  // group (4 lanes/group)
    int ch0 = l * 8;                  // 8 channels per lane
#pragma unroll
    for (int round = 0; round < 2; ++round) {
        int pixloc = round * 16 + half;
        int hw = hwb + pixloc;
        int h = hw >> 6, w = hw & 63;
        const float* lm = &lom[pixloc * NCOL];
        // softmax over P for this group
        float lg[9];
        float mx = -1e30f;
#pragma unroll
        for (int p = 0; p < 9; ++p) { lg[p] = lm[144 + g * 9 + p]; mx = fmaxf(mx, lg[p]); }
        float sum = 0.f;
#pragma unroll
        for (int p = 0; p < 9; ++p) { lg[p] = __expf(lg[p] - mx); sum += lg[p]; }
        float rs = 1.0f / sum;
        float acc2[8] = {};
#pragma unroll
        for (int p = 0; p < 9; ++p) {
            float ox = lm[g * 18 + p * 2];
            float oy = lm[g * 18 + p * 2 + 1];
            // padded coords; clamp into the zero ring == reference valid-mask
            float px = (float)(w + (p / 3)) + ox;
            float py = (float)(h + (p % 3)) + oy;
            float xf = floorf(px), yf = floorf(py);
            float wx = px - xf, wy = py - yf;
            int x0 = (int)xf, y0 = (int)yf;
            float m = lg[p] * rs;
            float w00 = m * (1.f - wy) * (1.f - wx);
            float w01 = m * (1.f - wy) * wx;
            float w10 = m * wy * (1.f - wx);
            float w11 = m * wy * wx;
#pragma unroll
            for (int corner = 0; corner < 4; ++corner) {
                int yi = min(max(y0 + (corner >> 1), 0), 65);
                int xi = min(max(x0 + (corner & 1), 0), 65);
                float cw = (corner == 0) ? w00 : (corner == 1) ? w01 : (corner == 2) ? w10 : w11;
                bf16x8 v = *(const bf16x8*)&base[((size_t)(yi * PW + xi)) * 256 + ch0];
#pragma unroll
                for (int j = 0; j < 8; ++j)
                    acc2[j] = fmaf(cw, bf2f((unsigned short)v[j]), acc2[j]);
            }
        }
        *(float4*)&ot[half * 260 + ch0]     = make_float4(acc2[0], acc2[1], acc2[2], acc2[3]);
        *(float4*)&ot[half * 260 + ch0 + 4] = make_float4(acc2[4], acc2[5], acc2[6], acc2[7]);
        __syncthreads();
        // write NCHW: 16 consecutive pixels per channel (64B segments)
        int px = tid & 15, crow = tid >> 4;   // crow 0..31
#pragma unroll
        for (int cc = 0; cc < 8; ++cc) {
            int c = cc * 32 + crow;
            out[((size_t)(n * CH + c)) * HW + hwb + round * 16 + px] = ot[px * 260 + c];
        }
        if (round == 0) __syncthreads();   // protect ot before next round's writes
    }
}

extern "C" void kernel_launch(void* const* d_in, const int* in_sizes, int n_in,
                              void* d_out, int out_size, void* d_ws, size_t ws_size,
                              hipStream_t stream) {
    const float* x      = (const float*)d_in[0];
    const float* dw_w   = (const float*)d_in[1];
    const float* dw_b   = (const float*)d_in[2];
    const float* gn_g   = (const float*)d_in[3];
    const float* gn_b   = (const float*)d_in[4];
    const float* off_w  = (const float*)d_in[5];
    const float* off_b  = (const float*)d_in[6];
    const float* mask_w = (const float*)d_in[7];
    const float* mask_b = (const float*)d_in[8];
    float* out = (float*)d_out;

    float* ws = (float*)d_ws;
    unsigned short* inp_nhwc = (unsigned short*)(ws + OFF_NHWC);
    unsigned short* Abf   = (unsigned short*)(ws + OFF_AB);
    unsigned short* Wc_bt = (unsigned short*)(ws + OFF_WB);
    float* bias     = ws + OFF_BI;
    float* partials = ws + OFF_PT;

    conv_prep_kernel<<<4096, 256, 0, stream>>>(x, dw_w, dw_b, off_w, off_b,
                                               mask_w, mask_b, Abf, inp_nhwc,
                                               Wc_bt, bias, partials);
    fused_gemm_dcn_kernel<<<512, 512, 0, stream>>>(Abf, Wc_bt, bias, partials,
                                                   gn_g, gn_b, inp_nhwc, out);
}